// Round 4
// baseline (200.744 us; speedup 1.0000x reference)
//
#include <hip/hip_runtime.h>
#include <math.h>

// ---------------------------------------------------------------------------
// AttentionBlock: GN(4,256) -> QKV 1x1 conv -> 2-head attn (N=1024, hd=128)
// -> proj -> +residual.  B=16, C=256, H=W=32 (N=1024), fp32 in/out.
// R4: attn split-j flash (no online max: scores bounded), LDS P-transpose
// instead of shfl re-frag; qkv fused with GroupNorm (xnt round-trip removed)
// and coalesced LDS-transpose epilogues for Q/K/V stores.
// ---------------------------------------------------------------------------

typedef __attribute__((ext_vector_type(8))) short bf16x8;   // 8 bf16 = 4 VGPRs
typedef __attribute__((ext_vector_type(4))) float f32x4;

__device__ __forceinline__ unsigned short f2bf(float f) {   // RNE-ish
    union { float f; unsigned u; } v; v.f = f;
    return (unsigned short)((v.u + 0x7FFFu + ((v.u >> 16) & 1u)) >> 16);
}
__device__ __forceinline__ unsigned bfbits(float f) {       // +half (round up)
    union { float f; unsigned u; } v; v.f = f;
    return v.u + 0x8000u;
}
// pack two floats -> (bf(a) | bf(b)<<16) in 3 VALU ops
__device__ __forceinline__ unsigned packbf(float a, float b) {
    return __builtin_amdgcn_perm(bfbits(b), bfbits(a), 0x07060302u);
}

__device__ __forceinline__ void gload_lds16(const void* g, void* l) {
    __builtin_amdgcn_global_load_lds(
        (const __attribute__((address_space(1))) unsigned int*)g,
        (__attribute__((address_space(3))) unsigned int*)l, 16, 0, 0);
}

// ---------------------------------------------------------------- GN stats
__global__ __launch_bounds__(256) void gn_stats(const float* __restrict__ x,
                                                float* __restrict__ acc) {
    int bg = blockIdx.x >> 3, ch = blockIdx.x & 7;
    const float4* xp = (const float4*)(x + (size_t)bg * 65536 + ch * 8192);
    float s = 0.f, s2 = 0.f;
#pragma unroll
    for (int i = 0; i < 8; i++) {
        float4 v = xp[threadIdx.x + i * 256];
        s  += v.x + v.y + v.z + v.w;
        s2 += v.x * v.x + v.y * v.y + v.z * v.z + v.w * v.w;
    }
    for (int m = 1; m < 64; m <<= 1) { s += __shfl_xor(s, m); s2 += __shfl_xor(s2, m); }
    __shared__ float ls[8];
    int w = threadIdx.x >> 6, lane = threadIdx.x & 63;
    if (lane == 0) { ls[w] = s; ls[4 + w] = s2; }
    __syncthreads();
    if (threadIdx.x == 0) {
        atomicAdd(&acc[bg * 2],     ls[0] + ls[1] + ls[2] + ls[3]);
        atomicAdd(&acc[bg * 2 + 1], ls[4] + ls[5] + ls[6] + ls[7]);
    }
}

// ------------------------------------------------------- weights fp32->bf16
__global__ __launch_bounds__(256) void wconv(const float* __restrict__ wq,
                                             const float* __restrict__ wk,
                                             const float* __restrict__ wv,
                                             const float* __restrict__ wp,
                                             unsigned short* __restrict__ oq,
                                             unsigned short* __restrict__ ok,
                                             unsigned short* __restrict__ ov,
                                             unsigned short* __restrict__ op,
                                             float* __restrict__ acc) {
    int idx = blockIdx.x * 256 + threadIdx.x;
    if (blockIdx.x == 0 && threadIdx.x < 128) acc[threadIdx.x] = 0.f;
    int which = idx >> 16, i = idx & 65535;
    const float* src = (which == 0) ? wq : (which == 1) ? wk : (which == 2) ? wv : wp;
    unsigned short* dst = (which == 0) ? oq : (which == 1) ? ok : (which == 2) ? ov : op;
    // fold softmax scale 512^-0.5 AND log2(e) into wq (softmax uses exp2)
    float scl = (which == 0) ? (0.044194173824159216f * 1.4426950408889634f) : 1.0f;
    dst[i] = f2bf(src[i] * scl);
}

// --------------------------------------------------- QKV GEMM fused with GN
// grid (16 nx, 6 my, 16 b). Block: 128 out-rows x 64 spatial. Normalizes its
// x-tile into LDS (b-frag layout), MFMA K-loop (W from L2), then coalesced
// LDS-transpose epilogue. my: sel=my>>1 (q/k/v), half=my&1 (head).
__global__ __launch_bounds__(256) void qkv_fused(const float* __restrict__ x,
                                                 const float* __restrict__ acc,
                                                 const float* __restrict__ gnw,
                                                 const float* __restrict__ gnb,
                                                 const unsigned short* __restrict__ wqb,
                                                 const unsigned short* __restrict__ wkb,
                                                 const unsigned short* __restrict__ wvb,
                                                 unsigned short* __restrict__ qt,
                                                 unsigned short* __restrict__ kt,
                                                 unsigned short* __restrict__ vv) {
    int b = blockIdx.z, my = blockIdx.y, nx = blockIdx.x;
    int sel = my >> 1, half = my & 1;
    int n0 = nx * 64;
    int t = threadIdx.x, w = t >> 6, lane = t & 63, quad = lane >> 4, c4 = lane & 15;
    __shared__ __align__(16) unsigned short sbuf[16896];   // xl[64][264] / epilogue
    __shared__ float gs[8];
    if (t < 8) {
        int g = t >> 1;
        float a0 = acc[(b * 4 + g) * 2], a1 = acc[(b * 4 + g) * 2 + 1];
        float mean = a0 * (1.f / 65536.f);
        float var = a1 * (1.f / 65536.f) - mean * mean;
        gs[t] = (t & 1) ? rsqrtf(var + 1e-5f) : mean;
    }
    __syncthreads();
    // ---- load + normalize x-tile -> xl[n 64][c pitch 264] bf16
    {
        int col = t & 15, crow = t >> 4;
#pragma unroll
        for (int p = 0; p < 16; p++) {
            int c = p * 16 + crow;
            int g = c >> 6;
            float sc = gs[g * 2 + 1] * gnw[c];
            float bs = gnb[c] - gs[g * 2] * sc;
            float4 v = *(const float4*)(x + ((size_t)b * 256 + c) * 1024 + n0 + col * 4);
            int nl = col * 4;
            sbuf[(nl + 0) * 264 + c] = (unsigned short)(bfbits(fmaf(v.x, sc, bs)) >> 16);
            sbuf[(nl + 1) * 264 + c] = (unsigned short)(bfbits(fmaf(v.y, sc, bs)) >> 16);
            sbuf[(nl + 2) * 264 + c] = (unsigned short)(bfbits(fmaf(v.z, sc, bs)) >> 16);
            sbuf[(nl + 3) * 264 + c] = (unsigned short)(bfbits(fmaf(v.w, sc, bs)) >> 16);
        }
    }
    __syncthreads();
    const unsigned short* wptr = (sel == 0) ? wqb : (sel == 1) ? wkb : wvb;
    int wm = (w >> 1) * 64, wn = (w & 1) * 32;
    int mbase = half * 128 + wm;
    f32x4 ac[4][2] = {};
    for (int k = 0; k < 256; k += 32) {
        bf16x8 af[4], bfr[2];
#pragma unroll
        for (int i = 0; i < 4; i++)
            af[i] = *(const bf16x8*)(wptr + (mbase + i * 16 + c4) * 256 + k + quad * 8);
#pragma unroll
        for (int i = 0; i < 2; i++)
            bfr[i] = *(const bf16x8*)&sbuf[(wn + i * 16 + c4) * 264 + k + quad * 8];
#pragma unroll
        for (int mi = 0; mi < 4; mi++)
#pragma unroll
            for (int ni = 0; ni < 2; ni++)
                ac[mi][ni] = __builtin_amdgcn_mfma_f32_16x16x32_bf16(
                    af[mi], bfr[ni], ac[mi][ni], 0, 0, 0);
    }
    __syncthreads();   // xl fully consumed; reuse sbuf for epilogue
    int bh = b * 2 + half;
    if (sel < 2) {
        // et[i 64][ch pitch 136]; acc rows are ch, cols are i
#pragma unroll
        for (int mi = 0; mi < 4; mi++)
#pragma unroll
            for (int ni = 0; ni < 2; ni++) {
                uint2 u;
                u.x = packbf(ac[mi][ni][0], ac[mi][ni][1]);
                u.y = packbf(ac[mi][ni][2], ac[mi][ni][3]);
                *(uint2*)&sbuf[(wn + ni * 16 + c4) * 136 + wm + mi * 16 + quad * 4] = u;
            }
        __syncthreads();
        unsigned short* dst0 = (sel == 0) ? qt : kt;
#pragma unroll
        for (int p = 0; p < 4; p++) {
            int i = p * 16 + (t >> 4), off = (t & 15) * 8;
            bf16x8 row = *(const bf16x8*)&sbuf[i * 136 + off];
            *(bf16x8*)(dst0 + ((size_t)bh * 1024 + n0 + i) * 128 + off) = row;
        }
    } else {
        // et2[ch 128][i pitch 72]
#pragma unroll
        for (int mi = 0; mi < 4; mi++)
#pragma unroll
            for (int ni = 0; ni < 2; ni++)
#pragma unroll
                for (int r = 0; r < 4; r++)
                    sbuf[(wm + mi * 16 + quad * 4 + r) * 72 + wn + ni * 16 + c4] =
                        f2bf(ac[mi][ni][r]);
        __syncthreads();
#pragma unroll
        for (int p = 0; p < 4; p++) {
            int ch = p * 32 + (t >> 3), off = (t & 7) * 8;
            bf16x8 row = *(const bf16x8*)&sbuf[ch * 72 + off];
            *(bf16x8*)(vv + ((size_t)bh * 128 + ch) * 1024 + n0 + off) = row;
        }
    }
}

// ------------------------------------------------------- flash attention v4
// grid (16,2,16), 4 waves. wave w: q-half qh=w&1 (32 rows), j-half jh=w>>1
// (64 of 128 j per tile). No online max (scores bounded: sigma~0.5, max~2.8).
// P re-frag through wave-private LDS transpose. Partner waves merge O,l by
// addition at the end.
__global__ __launch_bounds__(256) void attn_kernel(const unsigned short* __restrict__ qt,
                                                   const unsigned short* __restrict__ kt,
                                                   const unsigned short* __restrict__ vv,
                                                   unsigned short* __restrict__ ot) {
    int b = blockIdx.z, h = blockIdx.y, qb = blockIdx.x;
    int bh = b * 2 + h;
    int tid = threadIdx.x, w = tid >> 6, lane = tid & 63;
    int quad = lane >> 4, c4 = lane & 15;
    int qh = w & 1, jh = w >> 1;
    __shared__ __align__(16) unsigned short klds[16384];   // 32 KB K-tile
    __shared__ __align__(16) unsigned short vlds[16384];   // 32 KB V-tile
    __shared__ __align__(16) unsigned short plds[4608];    // 9 KB: per-wave P^T [16][72]

    const unsigned short* qp = qt + (size_t)bh * 1024 * 128;
    const unsigned short* kp = kt + (size_t)bh * 1024 * 128;
    const unsigned short* vp = vv + (size_t)bh * 128 * 1024;
    int i0 = qb * 64 + qh * 32;

    // Q B-frags for 32 rows: bq[iset][kk], i = i0 + iset*16 + c4
    bf16x8 bq[2][4];
#pragma unroll
    for (int iset = 0; iset < 2; iset++)
#pragma unroll
        for (int kk = 0; kk < 4; kk++)
            bq[iset][kk] = *(const bf16x8*)(qp + (size_t)(i0 + iset * 16 + c4) * 128 + kk * 32 + quad * 8);

    float lsum[2] = {0.f, 0.f};
    f32x4 oacc[2][8] = {};   // O[i = iset*16 + quad*4 + r][c = n*16 + c4]

    for (int jt = 0; jt < 8; jt++) {
        int j0 = jt * 128;
        __syncthreads();
#pragma unroll
        for (int t = 0; t < 16; t++) {
            int chunk = w * 16 + t;
            if (chunk < 32) {
                int n = chunk >> 2, kk = chunk & 3;
                const unsigned short* g = kp + (size_t)(j0 + n * 16 + c4) * 128 + kk * 32 + quad * 8;
                gload_lds16(g, &klds[chunk * 512]);
            } else {
                int cc = chunk - 32;
                int n = cc >> 2, w4 = cc & 3;
                const unsigned short* g = vp + (size_t)(n * 16 + c4) * 1024 + j0 + w4 * 32 + quad * 8;
                gload_lds16(g, &vlds[cc * 512]);
            }
        }
        __syncthreads();

        // ---- S^T for this wave's j-half: st[iset][n'], j = (jh*4+n')*16+quad*4+r, i = iset*16+c4
        f32x4 st[2][4] = {};
#pragma unroll
        for (int np = 0; np < 4; np++)
#pragma unroll
            for (int kk = 0; kk < 4; kk++) {
                bf16x8 ak = *(const bf16x8*)&klds[((jh * 4 + np) * 4 + kk) * 512 + lane * 8];
                st[0][np] = __builtin_amdgcn_mfma_f32_16x16x32_bf16(ak, bq[0][kk], st[0][np], 0, 0, 0);
                st[1][np] = __builtin_amdgcn_mfma_f32_16x16x32_bf16(ak, bq[1][kk], st[1][np], 0, 0, 0);
            }

        // ---- p = exp2(s) (log2e folded into wq), accumulate row-sum partials
#pragma unroll
        for (int iset = 0; iset < 2; iset++)
#pragma unroll
            for (int np = 0; np < 4; np++)
#pragma unroll
                for (int r = 0; r < 4; r++) {
                    float p = exp2f(st[iset][np][r]);
                    st[iset][np][r] = p;
                    lsum[iset] += p;
                }

        // ---- P^T via wave-private LDS: row = i-local (c4), col j_wave = np*16+quad*4+r
        bf16x8 pa[2][2];
#pragma unroll
        for (int iset = 0; iset < 2; iset++) {
#pragma unroll
            for (int np = 0; np < 4; np++) {
                uint2 u;
                u.x = packbf(st[iset][np][0], st[iset][np][1]);
                u.y = packbf(st[iset][np][2], st[iset][np][3]);
                *(uint2*)&plds[w * 1152 + c4 * 72 + np * 16 + quad * 4] = u;
            }
#pragma unroll
            for (int kw = 0; kw < 2; kw++)
                pa[iset][kw] = *(const bf16x8*)&plds[w * 1152 + c4 * 72 + kw * 32 + quad * 8];
        }

        // ---- PV: O += P * V^T over this wave's 64 j
#pragma unroll
        for (int kw = 0; kw < 2; kw++)
#pragma unroll
            for (int n = 0; n < 8; n++) {
                bf16x8 bv = *(const bf16x8*)&vlds[(n * 4 + jh * 2 + kw) * 512 + lane * 8];
                oacc[0][n] = __builtin_amdgcn_mfma_f32_16x16x32_bf16(pa[0][kw], bv, oacc[0][n], 0, 0, 0);
                oacc[1][n] = __builtin_amdgcn_mfma_f32_16x16x32_bf16(pa[1][kw], bv, oacc[1][n], 0, 0, 0);
            }
    }

    // ---- finish row sums within wave (reduce over quads)
#pragma unroll
    for (int iset = 0; iset < 2; iset++) {
        lsum[iset] += __shfl_xor(lsum[iset], 16);
        lsum[iset] += __shfl_xor(lsum[iset], 32);
    }

    // ---- merge partner j-halves (w, w+2) through LDS
    __syncthreads();
    float* kf = (float*)klds;
    float* vf = (float*)vlds;
    if (jh == 1) {
#pragma unroll
        for (int iset = 0; iset < 2; iset++) {
#pragma unroll
            for (int n = 0; n < 8; n++)
                *(f32x4*)&kf[((qh * 16 + iset * 8 + n) * 64 + lane) * 4] = oacc[iset][n];
            vf[qh * 128 + iset * 64 + lane] = lsum[iset];
        }
    }
    __syncthreads();
    if (jh == 0) {
#pragma unroll
        for (int iset = 0; iset < 2; iset++) {
#pragma unroll
            for (int n = 0; n < 8; n++) {
                f32x4 o2 = *(const f32x4*)&kf[((qh * 16 + iset * 8 + n) * 64 + lane) * 4];
                oacc[iset][n] += o2;
            }
            lsum[iset] += vf[qh * 128 + iset * 64 + lane];
        }
        float ir[2][4];
#pragma unroll
        for (int iset = 0; iset < 2; iset++) {
            float inv = 1.0f / lsum[iset];
#pragma unroll
            for (int r = 0; r < 4; r++) ir[iset][r] = __shfl(inv, quad * 4 + r);
        }
#pragma unroll
        for (int iset = 0; iset < 2; iset++)
#pragma unroll
            for (int n = 0; n < 8; n++)
#pragma unroll
                for (int r = 0; r < 4; r++) {
                    int i = i0 + iset * 16 + quad * 4 + r;
                    int c = h * 128 + n * 16 + c4;
                    ot[((size_t)b * 1024 + i) * 256 + c] = f2bf(oacc[iset][n][r] * ir[iset][r]);
                }
    }
}

// ------------------------------------------------------ proj + residual
__global__ __launch_bounds__(256) void proj_gemm(const unsigned short* __restrict__ wpb,
                                                 const unsigned short* __restrict__ ot,
                                                 const float* __restrict__ x,
                                                 float* __restrict__ out) {
    int b = blockIdx.z;
    int my = blockIdx.y;   // 0..1
    int nx = blockIdx.x;   // 0..15
    int tid = threadIdx.x;
    int w = tid >> 6, lane = tid & 63, quad = lane >> 4, c4 = lane & 15;
    int wm = (w >> 1) * 64, wn = (w & 1) * 32;
    int mbase = my * 128 + wm;
    int nbase = nx * 64 + wn;
    const unsigned short* ob = ot + (size_t)b * 1024 * 256;

    f32x4 acc[4][2] = {};
    for (int k = 0; k < 256; k += 32) {
        bf16x8 af[4], bfr[2];
#pragma unroll
        for (int i = 0; i < 4; i++)
            af[i] = *(const bf16x8*)(wpb + (mbase + i * 16 + c4) * 256 + k + quad * 8);
#pragma unroll
        for (int i = 0; i < 2; i++)
            bfr[i] = *(const bf16x8*)(ob + (size_t)(nbase + i * 16 + c4) * 256 + k + quad * 8);
#pragma unroll
        for (int mi = 0; mi < 4; mi++)
#pragma unroll
            for (int ni = 0; ni < 2; ni++)
                acc[mi][ni] = __builtin_amdgcn_mfma_f32_16x16x32_bf16(
                    af[mi], bfr[ni], acc[mi][ni], 0, 0, 0);
    }
#pragma unroll
    for (int mi = 0; mi < 4; mi++)
#pragma unroll
        for (int ni = 0; ni < 2; ni++)
#pragma unroll
            for (int r = 0; r < 4; r++) {
                int o = mbase + mi * 16 + quad * 4 + r;
                int i = nbase + ni * 16 + c4;
                size_t idx = ((size_t)b * 256 + o) * 1024 + i;
                out[idx] = acc[mi][ni][r] + x[idx];
            }
}

// ---------------------------------------------------------------------------
extern "C" void kernel_launch(void* const* d_in, const int* in_sizes, int n_in,
                              void* d_out, int out_size, void* d_ws, size_t ws_size,
                              hipStream_t stream) {
    const float* x   = (const float*)d_in[0];
    const float* gnw = (const float*)d_in[1];
    const float* gnb = (const float*)d_in[2];
    const float* wq  = (const float*)d_in[3];
    const float* wk  = (const float*)d_in[4];
    const float* wv  = (const float*)d_in[5];
    const float* wp  = (const float*)d_in[6];
    float* out = (float*)d_out;

    char* ws = (char*)d_ws;
    float* acc = (float*)ws;                                       //   512 B
    unsigned short* wqb = (unsigned short*)(ws + 512);             // 128 KiB each
    unsigned short* wkb = (unsigned short*)(ws + 512 + 131072);
    unsigned short* wvb = (unsigned short*)(ws + 512 + 2 * 131072);
    unsigned short* wpb = (unsigned short*)(ws + 512 + 3 * 131072);
    size_t base = 512 + 4 * 131072;
    const size_t SZ = (size_t)16 * 1024 * 256 * 2;  // 8 MiB each
    unsigned short* qt = (unsigned short*)(ws + base);
    unsigned short* kt = (unsigned short*)(ws + base + SZ);
    unsigned short* vv = (unsigned short*)(ws + base + 2 * SZ);
    unsigned short* ot = (unsigned short*)(ws + base + 3 * SZ);

    wconv<<<1024, 256, 0, stream>>>(wq, wk, wv, wp, wqb, wkb, wvb, wpb, acc);
    gn_stats<<<512, 256, 0, stream>>>(x, acc);
    qkv_fused<<<dim3(16, 6, 16), 256, 0, stream>>>(x, acc, gnw, gnb,
                                                   wqb, wkb, wvb, qt, kt, vv);
    attn_kernel<<<dim3(16, 2, 16), 256, 0, stream>>>(qt, kt, vv, ot);
    proj_gemm<<<dim3(16, 2, 16), 256, 0, stream>>>(wpb, ot, x, out);
}

// Round 5
// 174.575 us; speedup vs baseline: 1.1499x; 1.1499x over previous
//
#include <hip/hip_runtime.h>
#include <math.h>

// ---------------------------------------------------------------------------
// AttentionBlock: GN(4,256) -> QKV 1x1 conv -> 2-head attn (N=1024, hd=128)
// -> proj -> +residual.  B=16, C=256, H=W=32 (N=1024), fp32 in/out.
// R5: attn = R3 structure (shfl re-frag, full-j per wave) + no-online-max +
// 32KB LDS (j-tile 64) for 4 blocks/CU. qkv reads x ONCE (sel-loop inside).
// ---------------------------------------------------------------------------

typedef __attribute__((ext_vector_type(8))) short bf16x8;   // 8 bf16 = 4 VGPRs
typedef __attribute__((ext_vector_type(4))) float f32x4;

__device__ __forceinline__ unsigned short f2bf(float f) {   // RNE-ish
    union { float f; unsigned u; } v; v.f = f;
    return (unsigned short)((v.u + 0x7FFFu + ((v.u >> 16) & 1u)) >> 16);
}
__device__ __forceinline__ unsigned bfbits(float f) {       // +half (round up)
    union { float f; unsigned u; } v; v.f = f;
    return v.u + 0x8000u;
}
// pack two floats -> (bf(a) | bf(b)<<16) in 3 VALU ops
__device__ __forceinline__ unsigned packbf(float a, float b) {
    return __builtin_amdgcn_perm(bfbits(b), bfbits(a), 0x07060302u);
}

__device__ __forceinline__ void gload_lds16(const void* g, void* l) {
    __builtin_amdgcn_global_load_lds(
        (const __attribute__((address_space(1))) unsigned int*)g,
        (__attribute__((address_space(3))) unsigned int*)l, 16, 0, 0);
}

// ---------------------------------------------------------------- GN stats
__global__ __launch_bounds__(256) void gn_stats(const float* __restrict__ x,
                                                float* __restrict__ acc) {
    int bg = blockIdx.x >> 3, ch = blockIdx.x & 7;
    const float4* xp = (const float4*)(x + (size_t)bg * 65536 + ch * 8192);
    float s = 0.f, s2 = 0.f;
#pragma unroll
    for (int i = 0; i < 8; i++) {
        float4 v = xp[threadIdx.x + i * 256];
        s  += v.x + v.y + v.z + v.w;
        s2 += v.x * v.x + v.y * v.y + v.z * v.z + v.w * v.w;
    }
    for (int m = 1; m < 64; m <<= 1) { s += __shfl_xor(s, m); s2 += __shfl_xor(s2, m); }
    __shared__ float ls[8];
    int w = threadIdx.x >> 6, lane = threadIdx.x & 63;
    if (lane == 0) { ls[w] = s; ls[4 + w] = s2; }
    __syncthreads();
    if (threadIdx.x == 0) {
        atomicAdd(&acc[bg * 2],     ls[0] + ls[1] + ls[2] + ls[3]);
        atomicAdd(&acc[bg * 2 + 1], ls[4] + ls[5] + ls[6] + ls[7]);
    }
}

// ------------------------------------------------------- weights fp32->bf16
__global__ __launch_bounds__(256) void wconv(const float* __restrict__ wq,
                                             const float* __restrict__ wk,
                                             const float* __restrict__ wv,
                                             const float* __restrict__ wp,
                                             unsigned short* __restrict__ oq,
                                             unsigned short* __restrict__ ok,
                                             unsigned short* __restrict__ ov,
                                             unsigned short* __restrict__ op,
                                             float* __restrict__ acc) {
    int idx = blockIdx.x * 256 + threadIdx.x;
    if (blockIdx.x == 0 && threadIdx.x < 128) acc[threadIdx.x] = 0.f;
    int which = idx >> 16, i = idx & 65535;
    const float* src = (which == 0) ? wq : (which == 1) ? wk : (which == 2) ? wv : wp;
    unsigned short* dst = (which == 0) ? oq : (which == 1) ? ok : (which == 2) ? ov : op;
    // fold softmax scale 512^-0.5 AND log2(e) into wq (softmax uses exp2)
    float scl = (which == 0) ? (0.044194173824159216f * 1.4426950408889634f) : 1.0f;
    dst[i] = f2bf(src[i] * scl);
}

// --------------------------------------------------- QKV GEMM fused with GN
// grid (16 nx, 2 half, 16 b) = 512 blocks. Block: normalize x-tile (64n x
// 256c) into LDS ONCE, then loop sel in {q,k,v}: 128-row K-loop + coalesced
// LDS-transpose epilogue. x read exactly once.
__global__ __launch_bounds__(256) void qkv_fused(const float* __restrict__ x,
                                                 const float* __restrict__ acc,
                                                 const float* __restrict__ gnw,
                                                 const float* __restrict__ gnb,
                                                 const unsigned short* __restrict__ wqb,
                                                 const unsigned short* __restrict__ wkb,
                                                 const unsigned short* __restrict__ wvb,
                                                 unsigned short* __restrict__ qt,
                                                 unsigned short* __restrict__ kt,
                                                 unsigned short* __restrict__ vv) {
    int b = blockIdx.z, half = blockIdx.y, nx = blockIdx.x;
    int n0 = nx * 64;
    int t = threadIdx.x, w = t >> 6, lane = t & 63, quad = lane >> 4, c4 = lane & 15;
    __shared__ __align__(16) unsigned short xl[16896];    // [n 64][c pitch 264]
    __shared__ __align__(16) unsigned short ebuf[9216];   // epilogue scratch
    __shared__ float gs[8];
    if (t < 8) {
        int g = t >> 1;
        float a0 = acc[(b * 4 + g) * 2], a1 = acc[(b * 4 + g) * 2 + 1];
        float mean = a0 * (1.f / 65536.f);
        float var = a1 * (1.f / 65536.f) - mean * mean;
        gs[t] = (t & 1) ? rsqrtf(var + 1e-5f) : mean;
    }
    __syncthreads();
    // ---- load + normalize x-tile -> xl
    {
        int col = t & 15, crow = t >> 4;
#pragma unroll
        for (int p = 0; p < 16; p++) {
            int c = p * 16 + crow;
            int g = c >> 6;
            float sc = gs[g * 2 + 1] * gnw[c];
            float bs = gnb[c] - gs[g * 2] * sc;
            float4 v = *(const float4*)(x + ((size_t)b * 256 + c) * 1024 + n0 + col * 4);
            int nl = col * 4;
            xl[(nl + 0) * 264 + c] = (unsigned short)(bfbits(fmaf(v.x, sc, bs)) >> 16);
            xl[(nl + 1) * 264 + c] = (unsigned short)(bfbits(fmaf(v.y, sc, bs)) >> 16);
            xl[(nl + 2) * 264 + c] = (unsigned short)(bfbits(fmaf(v.z, sc, bs)) >> 16);
            xl[(nl + 3) * 264 + c] = (unsigned short)(bfbits(fmaf(v.w, sc, bs)) >> 16);
        }
    }
    __syncthreads();
    int wm = (w >> 1) * 64, wn = (w & 1) * 32;
    int mbase = half * 128 + wm;
    int bh = b * 2 + half;
#pragma unroll
    for (int sel = 0; sel < 3; sel++) {
        const unsigned short* wptr = (sel == 0) ? wqb : (sel == 1) ? wkb : wvb;
        f32x4 ac[4][2] = {};
#pragma unroll
        for (int k = 0; k < 256; k += 32) {
            bf16x8 af[4], bfr[2];
#pragma unroll
            for (int i = 0; i < 4; i++)
                af[i] = *(const bf16x8*)(wptr + (mbase + i * 16 + c4) * 256 + k + quad * 8);
#pragma unroll
            for (int i = 0; i < 2; i++)
                bfr[i] = *(const bf16x8*)&xl[(wn + i * 16 + c4) * 264 + k + quad * 8];
#pragma unroll
            for (int mi = 0; mi < 4; mi++)
#pragma unroll
                for (int ni = 0; ni < 2; ni++)
                    ac[mi][ni] = __builtin_amdgcn_mfma_f32_16x16x32_bf16(
                        af[mi], bfr[ni], ac[mi][ni], 0, 0, 0);
        }
        __syncthreads();   // ebuf free (previous sel's reads complete)
        if (sel < 2) {
            // ebuf as et[i 64][ch pitch 136]
#pragma unroll
            for (int mi = 0; mi < 4; mi++)
#pragma unroll
                for (int ni = 0; ni < 2; ni++) {
                    uint2 u;
                    u.x = packbf(ac[mi][ni][0], ac[mi][ni][1]);
                    u.y = packbf(ac[mi][ni][2], ac[mi][ni][3]);
                    *(uint2*)&ebuf[(wn + ni * 16 + c4) * 136 + wm + mi * 16 + quad * 4] = u;
                }
            __syncthreads();
            unsigned short* dst0 = (sel == 0) ? qt : kt;
#pragma unroll
            for (int p = 0; p < 4; p++) {
                int i = p * 16 + (t >> 4), off = (t & 15) * 8;
                bf16x8 row = *(const bf16x8*)&ebuf[i * 136 + off];
                *(bf16x8*)(dst0 + ((size_t)bh * 1024 + n0 + i) * 128 + off) = row;
            }
        } else {
            // ebuf as et2[ch 128][i pitch 72]
#pragma unroll
            for (int mi = 0; mi < 4; mi++)
#pragma unroll
                for (int ni = 0; ni < 2; ni++)
#pragma unroll
                    for (int r = 0; r < 4; r++)
                        ebuf[(wm + mi * 16 + quad * 4 + r) * 72 + wn + ni * 16 + c4] =
                            f2bf(ac[mi][ni][r]);
            __syncthreads();
#pragma unroll
            for (int p = 0; p < 4; p++) {
                int ch = p * 32 + (t >> 3), off = (t & 7) * 8;
                bf16x8 row = *(const bf16x8*)&ebuf[ch * 72 + off];
                *(bf16x8*)(vv + ((size_t)bh * 128 + ch) * 1024 + n0 + off) = row;
            }
        }
    }
}

// ------------------------------------------------------- flash attention v5
// R3 structure: grid (16,2,16), 4 waves, wave owns 16 q-rows, full-j loop.
// Deltas: no online max (scores bounded, validated R4); j-tile 64 -> 32 KB
// LDS -> 4 blocks/CU; packbf pack (3 VALU).
__global__ __launch_bounds__(256) void attn_kernel(const unsigned short* __restrict__ qt,
                                                   const unsigned short* __restrict__ kt,
                                                   const unsigned short* __restrict__ vv,
                                                   unsigned short* __restrict__ ot) {
    int b = blockIdx.z, h = blockIdx.y, qb = blockIdx.x;
    int bh = b * 2 + h;
    int tid = threadIdx.x, w = tid >> 6, lane = tid & 63;
    int quad = lane >> 4, c4 = lane & 15;
    __shared__ __align__(16) unsigned short klds[8192];   // 16 KB: K 64j x 128ch
    __shared__ __align__(16) unsigned short vlds[8192];   // 16 KB: V 128ch x 64j

    const unsigned short* qp = qt + (size_t)bh * 1024 * 128;
    const unsigned short* kp = kt + (size_t)bh * 1024 * 128;
    const unsigned short* vp = vv + (size_t)bh * 128 * 1024;
    int i0 = qb * 64 + w * 16;

    // Q B-frags (16 rows), kept in regs: i = i0 + c4, k = kk*32 + quad*8
    bf16x8 bq[4];
#pragma unroll
    for (int kk = 0; kk < 4; kk++)
        bq[kk] = *(const bf16x8*)(qp + (size_t)(i0 + c4) * 128 + kk * 32 + quad * 8);

    float lsum = 0.f;        // row i = i0 + c4 partial (dup x4 quads)
    f32x4 oacc[8] = {};      // O[i = quad*4+r][c = n*16 + c4]

    for (int jt = 0; jt < 16; jt++) {
        int j0 = jt * 64;
        __syncthreads();   // previous tile fully consumed
        // 32 chunks of 1 KB, 8 per wave; waves 0-1 stage K, 2-3 stage V.
#pragma unroll
        for (int t = 0; t < 8; t++) {
            int chunk = w * 8 + t;
            if (chunk < 16) {
                int np = chunk >> 2, kk = chunk & 3;
                const unsigned short* g = kp + (size_t)(j0 + np * 16 + c4) * 128 + kk * 32 + quad * 8;
                gload_lds16(g, &klds[chunk * 512]);
            } else {
                int cc = chunk - 16;
                int n = cc >> 1, kw = cc & 1;
                const unsigned short* g = vp + (size_t)(n * 16 + c4) * 1024 + j0 + kw * 32 + quad * 8;
                gload_lds16(g, &vlds[cc * 512]);
            }
        }
        __syncthreads();   // staging visible

        // ---- S^T: st[np], j = j0 + np*16 + quad*4 + r, i = i0 + c4
        f32x4 st[4] = {};
#pragma unroll
        for (int np = 0; np < 4; np++)
#pragma unroll
            for (int kk = 0; kk < 4; kk++) {
                bf16x8 ak = *(const bf16x8*)&klds[(np * 4 + kk) * 512 + lane * 8];
                st[np] = __builtin_amdgcn_mfma_f32_16x16x32_bf16(ak, bq[kk], st[np], 0, 0, 0);
            }

        // ---- p = exp2(s) (log2e folded into wq); accumulate row sums
#pragma unroll
        for (int np = 0; np < 4; np++)
#pragma unroll
            for (int r = 0; r < 4; r++) {
                float p = exp2f(st[np][r]);
                st[np][r] = p;
                lsum += p;
            }

        // ---- pack np pairs; re-frag via shfl (dest-side half select)
        unsigned pk2[2][4];
#pragma unroll
        for (int kw = 0; kw < 2; kw++)
#pragma unroll
            for (int r = 0; r < 4; r++)
                pk2[kw][r] = packbf(st[kw * 2][r], st[kw * 2 + 1][r]);

        int sbase = ((lane & 16) ? 32 : 0) + c4;
        bool hi = (lane & 32) != 0;
#pragma unroll
        for (int kw = 0; kw < 2; kw++) {
            bf16x8 pa;
#pragma unroll
            for (int t = 0; t < 4; t++) {
                unsigned u  = (unsigned)__shfl((int)pk2[kw][t], sbase);
                unsigned u2 = (unsigned)__shfl((int)pk2[kw][t], sbase + 16);
                pa[t]     = (short)(hi ? (u >> 16)  : (u & 0xffffu));
                pa[4 + t] = (short)(hi ? (u2 >> 16) : (u2 & 0xffffu));
            }
#pragma unroll
            for (int n = 0; n < 8; n++) {
                bf16x8 bv = *(const bf16x8*)&vlds[(n * 2 + kw) * 512 + lane * 8];
                oacc[n] = __builtin_amdgcn_mfma_f32_16x16x32_bf16(pa, bv, oacc[n], 0, 0, 0);
            }
        }
    }

    // ---- finish row sums (reduce over quads), epilogue
    lsum += __shfl_xor(lsum, 16);
    lsum += __shfl_xor(lsum, 32);
    float inv = 1.0f / lsum;
    float ir[4];
#pragma unroll
    for (int r = 0; r < 4; r++) ir[r] = __shfl(inv, quad * 4 + r);
#pragma unroll
    for (int n = 0; n < 8; n++)
#pragma unroll
        for (int r = 0; r < 4; r++) {
            int i = i0 + quad * 4 + r;
            int c = h * 128 + n * 16 + c4;
            ot[((size_t)b * 1024 + i) * 256 + c] = f2bf(oacc[n][r] * ir[r]);
        }
}

// ------------------------------------------------------ proj + residual
__global__ __launch_bounds__(256) void proj_gemm(const unsigned short* __restrict__ wpb,
                                                 const unsigned short* __restrict__ ot,
                                                 const float* __restrict__ x,
                                                 float* __restrict__ out) {
    int b = blockIdx.z;
    int my = blockIdx.y;   // 0..1
    int nx = blockIdx.x;   // 0..15
    int tid = threadIdx.x;
    int w = tid >> 6, lane = tid & 63, quad = lane >> 4, c4 = lane & 15;
    int wm = (w >> 1) * 64, wn = (w & 1) * 32;
    int mbase = my * 128 + wm;
    int nbase = nx * 64 + wn;
    const unsigned short* ob = ot + (size_t)b * 1024 * 256;

    f32x4 acc[4][2] = {};
    for (int k = 0; k < 256; k += 32) {
        bf16x8 af[4], bfr[2];
#pragma unroll
        for (int i = 0; i < 4; i++)
            af[i] = *(const bf16x8*)(wpb + (mbase + i * 16 + c4) * 256 + k + quad * 8);
#pragma unroll
        for (int i = 0; i < 2; i++)
            bfr[i] = *(const bf16x8*)(ob + (size_t)(nbase + i * 16 + c4) * 256 + k + quad * 8);
#pragma unroll
        for (int mi = 0; mi < 4; mi++)
#pragma unroll
            for (int ni = 0; ni < 2; ni++)
                acc[mi][ni] = __builtin_amdgcn_mfma_f32_16x16x32_bf16(
                    af[mi], bfr[ni], acc[mi][ni], 0, 0, 0);
    }
#pragma unroll
    for (int mi = 0; mi < 4; mi++)
#pragma unroll
        for (int ni = 0; ni < 2; ni++)
#pragma unroll
            for (int r = 0; r < 4; r++) {
                int o = mbase + mi * 16 + quad * 4 + r;
                int i = nbase + ni * 16 + c4;
                size_t idx = ((size_t)b * 256 + o) * 1024 + i;
                out[idx] = acc[mi][ni][r] + x[idx];
            }
}

// ---------------------------------------------------------------------------
extern "C" void kernel_launch(void* const* d_in, const int* in_sizes, int n_in,
                              void* d_out, int out_size, void* d_ws, size_t ws_size,
                              hipStream_t stream) {
    const float* x   = (const float*)d_in[0];
    const float* gnw = (const float*)d_in[1];
    const float* gnb = (const float*)d_in[2];
    const float* wq  = (const float*)d_in[3];
    const float* wk  = (const float*)d_in[4];
    const float* wv  = (const float*)d_in[5];
    const float* wp  = (const float*)d_in[6];
    float* out = (float*)d_out;

    char* ws = (char*)d_ws;
    float* acc = (float*)ws;                                       //   512 B
    unsigned short* wqb = (unsigned short*)(ws + 512);             // 128 KiB each
    unsigned short* wkb = (unsigned short*)(ws + 512 + 131072);
    unsigned short* wvb = (unsigned short*)(ws + 512 + 2 * 131072);
    unsigned short* wpb = (unsigned short*)(ws + 512 + 3 * 131072);
    size_t base = 512 + 4 * 131072;
    const size_t SZ = (size_t)16 * 1024 * 256 * 2;  // 8 MiB each
    unsigned short* qt = (unsigned short*)(ws + base);
    unsigned short* kt = (unsigned short*)(ws + base + SZ);
    unsigned short* vv = (unsigned short*)(ws + base + 2 * SZ);
    unsigned short* ot = (unsigned short*)(ws + base + 3 * SZ);

    wconv<<<1024, 256, 0, stream>>>(wq, wk, wv, wp, wqb, wkb, wvb, wpb, acc);
    gn_stats<<<512, 256, 0, stream>>>(x, acc);
    qkv_fused<<<dim3(16, 2, 16), 256, 0, stream>>>(x, acc, gnw, gnb,
                                                   wqb, wkb, wvb, qt, kt, vv);
    attn_kernel<<<dim3(16, 2, 16), 256, 0, stream>>>(qt, kt, vv, ot);
    proj_gemm<<<dim3(16, 2, 16), 256, 0, stream>>>(wpb, ot, x, out);
}

// Round 6
// 165.321 us; speedup vs baseline: 1.2143x; 1.0560x over previous
//
#include <hip/hip_runtime.h>
#include <math.h>

// ---------------------------------------------------------------------------
// AttentionBlock: GN(4,256) -> QKV 1x1 conv -> 2-head attn (N=1024, hd=128)
// -> proj -> +residual.  B=16, C=256, H=W=32 (N=1024), fp32 in/out.
// R6: attn = R5 mapping + double-buffered prefetch staging (1 barrier/jt) +
// XCD-aware block swizzle (K/V L2-resident per XCD). qkv computes Q/K/V in
// one K-loop (2 barriers). prep = wconv+gn_stats merged, slot-based stats.
// ---------------------------------------------------------------------------

typedef __attribute__((ext_vector_type(8))) short bf16x8;   // 8 bf16 = 4 VGPRs
typedef __attribute__((ext_vector_type(4))) float f32x4;

__device__ __forceinline__ unsigned short f2bf(float f) {   // RNE-ish
    union { float f; unsigned u; } v; v.f = f;
    return (unsigned short)((v.u + 0x7FFFu + ((v.u >> 16) & 1u)) >> 16);
}
__device__ __forceinline__ unsigned bfbits(float f) {       // +half (round up)
    union { float f; unsigned u; } v; v.f = f;
    return v.u + 0x8000u;
}
// pack two floats -> (bf(a) | bf(b)<<16) in 3 VALU ops
__device__ __forceinline__ unsigned packbf(float a, float b) {
    return __builtin_amdgcn_perm(bfbits(b), bfbits(a), 0x07060302u);
}

__device__ __forceinline__ void gload_lds16(const void* g, void* l) {
    __builtin_amdgcn_global_load_lds(
        (const __attribute__((address_space(1))) unsigned int*)g,
        (__attribute__((address_space(3))) unsigned int*)l, 16, 0, 0);
}

// ------------------------------------------- prep: weights->bf16 + GN stats
// grid 768: blocks [0,256) convert weights (float4), [256,768) = 512 stat
// blocks writing per-block partial sums to slots (no atomics, no init dep).
__global__ __launch_bounds__(256) void prep(const float* __restrict__ wq,
                                            const float* __restrict__ wk,
                                            const float* __restrict__ wv,
                                            const float* __restrict__ wp,
                                            unsigned short* __restrict__ oq,
                                            unsigned short* __restrict__ ok,
                                            unsigned short* __restrict__ ov,
                                            unsigned short* __restrict__ op,
                                            const float* __restrict__ x,
                                            float* __restrict__ acc) {
    int bid = blockIdx.x;
    if (bid < 256) {
        int idx = bid * 1024 + threadIdx.x * 4;
        int which = idx >> 16, i = idx & 65535;
        const float* src = (which == 0) ? wq : (which == 1) ? wk : (which == 2) ? wv : wp;
        unsigned short* dst = (which == 0) ? oq : (which == 1) ? ok : (which == 2) ? ov : op;
        // fold softmax scale 512^-0.5 AND log2(e) into wq (softmax uses exp2)
        float scl = (which == 0) ? (0.044194173824159216f * 1.4426950408889634f) : 1.0f;
        float4 v = *(const float4*)(src + i);
        ushort4 o;
        o.x = f2bf(v.x * scl); o.y = f2bf(v.y * scl);
        o.z = f2bf(v.z * scl); o.w = f2bf(v.w * scl);
        *(ushort4*)(dst + i) = o;
    } else {
        int bid2 = bid - 256;                  // [0,512)
        int bg = bid2 >> 3, ch = bid2 & 7;
        const float4* xp = (const float4*)(x + (size_t)bg * 65536 + ch * 8192);
        float s = 0.f, s2 = 0.f;
#pragma unroll
        for (int i = 0; i < 8; i++) {
            float4 v = xp[threadIdx.x + i * 256];
            s  += v.x + v.y + v.z + v.w;
            s2 += v.x * v.x + v.y * v.y + v.z * v.z + v.w * v.w;
        }
        for (int m = 1; m < 64; m <<= 1) { s += __shfl_xor(s, m); s2 += __shfl_xor(s2, m); }
        __shared__ float ls[8];
        int w = threadIdx.x >> 6, lane = threadIdx.x & 63;
        if (lane == 0) { ls[w] = s; ls[4 + w] = s2; }
        __syncthreads();
        if (threadIdx.x == 0) {
            acc[bg * 16 + ch * 2]     = ls[0] + ls[1] + ls[2] + ls[3];
            acc[bg * 16 + ch * 2 + 1] = ls[4] + ls[5] + ls[6] + ls[7];
        }
    }
}

// --------------------------------------------------- QKV GEMM fused with GN
// grid (16 nx, 2 half, 16 b) = 512 blocks. Normalize x-tile (64n x 256c) into
// LDS once; ONE K-loop computes Q,K,V accumulators (3 independent MFMA
// chains); 2 barriers; coalesced LDS-transpose epilogues.
__global__ __launch_bounds__(256) void qkv_fused(const float* __restrict__ x,
                                                 const float* __restrict__ acc,
                                                 const float* __restrict__ gnw,
                                                 const float* __restrict__ gnb,
                                                 const unsigned short* __restrict__ wqb,
                                                 const unsigned short* __restrict__ wkb,
                                                 const unsigned short* __restrict__ wvb,
                                                 unsigned short* __restrict__ qt,
                                                 unsigned short* __restrict__ kt,
                                                 unsigned short* __restrict__ vv) {
    int b = blockIdx.z, half = blockIdx.y, nx = blockIdx.x;
    int n0 = nx * 64;
    int t = threadIdx.x, w = t >> 6, lane = t & 63, quad = lane >> 4, c4 = lane & 15;
    __shared__ __align__(16) unsigned short xl[17408];   // p1: [64][264]; p2: Q-et@0, K-et@8704 ([64][136])
    __shared__ __align__(16) unsigned short ebuf[9216];  // V-et2 [128][72]
    __shared__ float gs[8];
    if (t < 4) {
        float s0 = 0.f, s1 = 0.f;
#pragma unroll
        for (int p = 0; p < 8; p++) {
            s0 += acc[(b * 4 + t) * 16 + p * 2];
            s1 += acc[(b * 4 + t) * 16 + p * 2 + 1];
        }
        float mean = s0 * (1.f / 65536.f);
        float var = s1 * (1.f / 65536.f) - mean * mean;
        gs[2 * t] = mean;
        gs[2 * t + 1] = rsqrtf(var + 1e-5f);
    }
    __syncthreads();
    // ---- load + normalize x-tile -> xl [n 64][c pitch 264]
    {
        int col = t & 15, crow = t >> 4;
#pragma unroll
        for (int p = 0; p < 16; p++) {
            int c = p * 16 + crow;
            int g = c >> 6;
            float sc = gs[g * 2 + 1] * gnw[c];
            float bs = gnb[c] - gs[g * 2] * sc;
            float4 v = *(const float4*)(x + ((size_t)b * 256 + c) * 1024 + n0 + col * 4);
            int nl = col * 4;
            xl[(nl + 0) * 264 + c] = (unsigned short)(bfbits(fmaf(v.x, sc, bs)) >> 16);
            xl[(nl + 1) * 264 + c] = (unsigned short)(bfbits(fmaf(v.y, sc, bs)) >> 16);
            xl[(nl + 2) * 264 + c] = (unsigned short)(bfbits(fmaf(v.z, sc, bs)) >> 16);
            xl[(nl + 3) * 264 + c] = (unsigned short)(bfbits(fmaf(v.w, sc, bs)) >> 16);
        }
    }
    __syncthreads();
    int wm = (w >> 1) * 64, wn = (w & 1) * 32;
    int mbase = half * 128 + wm;
    int bh = b * 2 + half;
    f32x4 aq[4][2] = {}, akk[4][2] = {}, av[4][2] = {};
#pragma unroll
    for (int k = 0; k < 256; k += 32) {
        bf16x8 bfr[2];
#pragma unroll
        for (int i = 0; i < 2; i++)
            bfr[i] = *(const bf16x8*)&xl[(wn + i * 16 + c4) * 264 + k + quad * 8];
#pragma unroll
        for (int mi = 0; mi < 4; mi++) {
            bf16x8 afq = *(const bf16x8*)(wqb + (mbase + mi * 16 + c4) * 256 + k + quad * 8);
            bf16x8 afk = *(const bf16x8*)(wkb + (mbase + mi * 16 + c4) * 256 + k + quad * 8);
            bf16x8 afv = *(const bf16x8*)(wvb + (mbase + mi * 16 + c4) * 256 + k + quad * 8);
#pragma unroll
            for (int ni = 0; ni < 2; ni++) {
                aq[mi][ni]  = __builtin_amdgcn_mfma_f32_16x16x32_bf16(afq, bfr[ni], aq[mi][ni], 0, 0, 0);
                akk[mi][ni] = __builtin_amdgcn_mfma_f32_16x16x32_bf16(afk, bfr[ni], akk[mi][ni], 0, 0, 0);
                av[mi][ni]  = __builtin_amdgcn_mfma_f32_16x16x32_bf16(afv, bfr[ni], av[mi][ni], 0, 0, 0);
            }
        }
    }
    __syncthreads();   // xl reads done; reuse xl + ebuf for epilogue
#pragma unroll
    for (int mi = 0; mi < 4; mi++)
#pragma unroll
        for (int ni = 0; ni < 2; ni++) {
            int row = wn + ni * 16 + c4;          // i-local
            int col = wm + mi * 16 + quad * 4;    // ch
            uint2 uq, uk;
            uq.x = packbf(aq[mi][ni][0], aq[mi][ni][1]);
            uq.y = packbf(aq[mi][ni][2], aq[mi][ni][3]);
            uk.x = packbf(akk[mi][ni][0], akk[mi][ni][1]);
            uk.y = packbf(akk[mi][ni][2], akk[mi][ni][3]);
            *(uint2*)&xl[row * 136 + col] = uq;
            *(uint2*)&xl[8704 + row * 136 + col] = uk;
#pragma unroll
            for (int r = 0; r < 4; r++)
                ebuf[(col + r) * 72 + row] = f2bf(av[mi][ni][r]);
        }
    __syncthreads();
#pragma unroll
    for (int p = 0; p < 4; p++) {
        int i = p * 16 + (t >> 4), off = (t & 15) * 8;
        *(bf16x8*)(qt + ((size_t)bh * 1024 + n0 + i) * 128 + off) =
            *(const bf16x8*)&xl[i * 136 + off];
        *(bf16x8*)(kt + ((size_t)bh * 1024 + n0 + i) * 128 + off) =
            *(const bf16x8*)&xl[8704 + i * 136 + off];
    }
#pragma unroll
    for (int p = 0; p < 4; p++) {
        int ch = p * 32 + (t >> 3), off = (t & 7) * 8;
        *(bf16x8*)(vv + ((size_t)bh * 128 + ch) * 1024 + n0 + off) =
            *(const bf16x8*)&ebuf[ch * 72 + off];
    }
}

// ------------------------------------------------------- flash attention v6
// 1D grid 512, XCD-swizzled so each XCD's 64 blocks share 4 (b,h) pairs
// (Q+K+V 3MB < 4MB L2/XCD). 4 waves, wave owns 16 q-rows, j-tile 64,
// double-buffered K/V staging: prefetch jt+1 issued before compute of jt,
// ONE barrier per jt. No online max (validated R4/R5). shfl P re-frag.
__global__ __launch_bounds__(256) void attn_kernel(const unsigned short* __restrict__ qt,
                                                   const unsigned short* __restrict__ kt,
                                                   const unsigned short* __restrict__ vv,
                                                   unsigned short* __restrict__ ot) {
    int L = blockIdx.x;
    int xcd = L & 7, jj = L >> 3;
    int bh = (jj >> 4) * 8 + xcd;       // 4 bh per XCD
    int qb = jj & 15;
    int b = bh >> 1, h = bh & 1;
    int tid = threadIdx.x, w = tid >> 6, lane = tid & 63;
    int quad = lane >> 4, c4 = lane & 15;
    __shared__ __align__(16) unsigned short klds[2][8192];   // 2 x 16 KB
    __shared__ __align__(16) unsigned short vlds[2][8192];   // 2 x 16 KB

    const unsigned short* qp = qt + (size_t)bh * 1024 * 128;
    const unsigned short* kp = kt + (size_t)bh * 1024 * 128;
    const unsigned short* vp = vv + (size_t)bh * 128 * 1024;
    int i0 = qb * 64 + w * 16;

    // Q B-frags (16 rows) kept in regs: i = i0 + c4, k = kk*32 + quad*8
    bf16x8 bq[4];
#pragma unroll
    for (int kk = 0; kk < 4; kk++)
        bq[kk] = *(const bf16x8*)(qp + (size_t)(i0 + c4) * 128 + kk * 32 + quad * 8);

    float lsum = 0.f;        // row i = i0 + c4 partial (dup x4 quads)
    f32x4 oacc[8] = {};      // O[i = quad*4+r][c = n*16 + c4]

    // ---- prefetch tile 0 into buffer 0
#pragma unroll
    for (int t = 0; t < 8; t++) {
        int chunk = w * 8 + t;
        if (chunk < 16) {
            int np = chunk >> 2, kk = chunk & 3;
            gload_lds16(kp + (size_t)(np * 16 + c4) * 128 + kk * 32 + quad * 8,
                        &klds[0][chunk * 512]);
        } else {
            int cc = chunk - 16, n = cc >> 1, kw = cc & 1;
            gload_lds16(vp + (size_t)(n * 16 + c4) * 1024 + kw * 32 + quad * 8,
                        &vlds[0][cc * 512]);
        }
    }

    for (int jt = 0; jt < 16; jt++) {
        int cur = jt & 1;
        __syncthreads();   // staging of cur visible; prev reads of next-buf done
        // ---- issue prefetch for jt+1 (drained at NEXT barrier, after compute)
        if (jt < 15) {
            int j0n = (jt + 1) * 64, nb = cur ^ 1;
#pragma unroll
            for (int t = 0; t < 8; t++) {
                int chunk = w * 8 + t;
                if (chunk < 16) {
                    int np = chunk >> 2, kk = chunk & 3;
                    gload_lds16(kp + (size_t)(j0n + np * 16 + c4) * 128 + kk * 32 + quad * 8,
                                &klds[nb][chunk * 512]);
                } else {
                    int cc = chunk - 16, n = cc >> 1, kw = cc & 1;
                    gload_lds16(vp + (size_t)(n * 16 + c4) * 1024 + j0n + kw * 32 + quad * 8,
                                &vlds[nb][cc * 512]);
                }
            }
        }

        // ---- S^T: st[np], j = jt*64 + np*16 + quad*4 + r, i = i0 + c4
        f32x4 st[4] = {};
#pragma unroll
        for (int np = 0; np < 4; np++)
#pragma unroll
            for (int kk = 0; kk < 4; kk++) {
                bf16x8 ak = *(const bf16x8*)&klds[cur][(np * 4 + kk) * 512 + lane * 8];
                st[np] = __builtin_amdgcn_mfma_f32_16x16x32_bf16(ak, bq[kk], st[np], 0, 0, 0);
            }

        // ---- p = exp2(s) (log2e folded into wq); accumulate row sums
#pragma unroll
        for (int np = 0; np < 4; np++)
#pragma unroll
            for (int r = 0; r < 4; r++) {
                float p = exp2f(st[np][r]);
                st[np][r] = p;
                lsum += p;
            }

        // ---- pack np pairs; re-frag via shfl (dest-side half select)
        unsigned pk2[2][4];
#pragma unroll
        for (int kw = 0; kw < 2; kw++)
#pragma unroll
            for (int r = 0; r < 4; r++)
                pk2[kw][r] = packbf(st[kw * 2][r], st[kw * 2 + 1][r]);

        int sbase = ((lane & 16) ? 32 : 0) + c4;
        bool hi = (lane & 32) != 0;
#pragma unroll
        for (int kw = 0; kw < 2; kw++) {
            bf16x8 pa;
#pragma unroll
            for (int t = 0; t < 4; t++) {
                unsigned u  = (unsigned)__shfl((int)pk2[kw][t], sbase);
                unsigned u2 = (unsigned)__shfl((int)pk2[kw][t], sbase + 16);
                pa[t]     = (short)(hi ? (u >> 16)  : (u & 0xffffu));
                pa[4 + t] = (short)(hi ? (u2 >> 16) : (u2 & 0xffffu));
            }
#pragma unroll
            for (int n = 0; n < 8; n++) {
                bf16x8 bv = *(const bf16x8*)&vlds[cur][(n * 2 + kw) * 512 + lane * 8];
                oacc[n] = __builtin_amdgcn_mfma_f32_16x16x32_bf16(pa, bv, oacc[n], 0, 0, 0);
            }
        }
    }

    // ---- finish row sums (reduce over quads), epilogue
    lsum += __shfl_xor(lsum, 16);
    lsum += __shfl_xor(lsum, 32);
    float inv = 1.0f / lsum;
    float ir[4];
#pragma unroll
    for (int r = 0; r < 4; r++) ir[r] = __shfl(inv, quad * 4 + r);
#pragma unroll
    for (int n = 0; n < 8; n++)
#pragma unroll
        for (int r = 0; r < 4; r++) {
            int i = i0 + quad * 4 + r;
            int c = h * 128 + n * 16 + c4;
            ot[((size_t)b * 1024 + i) * 256 + c] = f2bf(oacc[n][r] * ir[r]);
        }
}

// ------------------------------------------------------ proj + residual
__global__ __launch_bounds__(256) void proj_gemm(const unsigned short* __restrict__ wpb,
                                                 const unsigned short* __restrict__ ot,
                                                 const float* __restrict__ x,
                                                 float* __restrict__ out) {
    int b = blockIdx.z;
    int my = blockIdx.y;   // 0..1
    int nx = blockIdx.x;   // 0..15
    int tid = threadIdx.x;
    int w = tid >> 6, lane = tid & 63, quad = lane >> 4, c4 = lane & 15;
    int wm = (w >> 1) * 64, wn = (w & 1) * 32;
    int mbase = my * 128 + wm;
    int nbase = nx * 64 + wn;
    const unsigned short* ob = ot + (size_t)b * 1024 * 256;

    f32x4 acc[4][2] = {};
#pragma unroll
    for (int k = 0; k < 256; k += 32) {
        bf16x8 af[4], bfr[2];
#pragma unroll
        for (int i = 0; i < 4; i++)
            af[i] = *(const bf16x8*)(wpb + (mbase + i * 16 + c4) * 256 + k + quad * 8);
#pragma unroll
        for (int i = 0; i < 2; i++)
            bfr[i] = *(const bf16x8*)(ob + (size_t)(nbase + i * 16 + c4) * 256 + k + quad * 8);
#pragma unroll
        for (int mi = 0; mi < 4; mi++)
#pragma unroll
            for (int ni = 0; ni < 2; ni++)
                acc[mi][ni] = __builtin_amdgcn_mfma_f32_16x16x32_bf16(
                    af[mi], bfr[ni], acc[mi][ni], 0, 0, 0);
    }
#pragma unroll
    for (int mi = 0; mi < 4; mi++)
#pragma unroll
        for (int ni = 0; ni < 2; ni++)
#pragma unroll
            for (int r = 0; r < 4; r++) {
                int o = mbase + mi * 16 + quad * 4 + r;
                int i = nbase + ni * 16 + c4;
                size_t idx = ((size_t)b * 256 + o) * 1024 + i;
                out[idx] = acc[mi][ni][r] + x[idx];
            }
}

// ---------------------------------------------------------------------------
extern "C" void kernel_launch(void* const* d_in, const int* in_sizes, int n_in,
                              void* d_out, int out_size, void* d_ws, size_t ws_size,
                              hipStream_t stream) {
    const float* x   = (const float*)d_in[0];
    const float* gnw = (const float*)d_in[1];
    const float* gnb = (const float*)d_in[2];
    const float* wq  = (const float*)d_in[3];
    const float* wk  = (const float*)d_in[4];
    const float* wv  = (const float*)d_in[5];
    const float* wp  = (const float*)d_in[6];
    float* out = (float*)d_out;

    char* ws = (char*)d_ws;
    float* acc = (float*)ws;                                        //   4 KiB
    unsigned short* wqb = (unsigned short*)(ws + 4096);             // 128 KiB each
    unsigned short* wkb = (unsigned short*)(ws + 4096 + 131072);
    unsigned short* wvb = (unsigned short*)(ws + 4096 + 2 * 131072);
    unsigned short* wpb = (unsigned short*)(ws + 4096 + 3 * 131072);
    size_t base = 4096 + 4 * 131072;
    const size_t SZ = (size_t)16 * 1024 * 256 * 2;  // 8 MiB each
    unsigned short* qt = (unsigned short*)(ws + base);
    unsigned short* kt = (unsigned short*)(ws + base + SZ);
    unsigned short* vv = (unsigned short*)(ws + base + 2 * SZ);
    unsigned short* ot = (unsigned short*)(ws + base + 3 * SZ);

    prep<<<768, 256, 0, stream>>>(wq, wk, wv, wp, wqb, wkb, wvb, wpb, x, acc);
    qkv_fused<<<dim3(16, 2, 16), 256, 0, stream>>>(x, acc, gnw, gnb,
                                                   wqb, wkb, wvb, qt, kt, vv);
    attn_kernel<<<512, 256, 0, stream>>>(qt, kt, vv, ot);
    proj_gemm<<<dim3(16, 2, 16), 256, 0, stream>>>(wpb, ot, x, out);
}